// Round 3
// baseline (440.700 us; speedup 1.0000x reference)
//
#include <hip/hip_runtime.h>
#include <math.h>

#define BB 32
#define CC 4
#define HH 64
#define WW 512
#define HW (HH * WW)

// ---------------- softmax over W (last axis), one wave (64 lanes) per row ----------------
__global__ __launch_bounds__(256) void softmax_rows(const float* __restrict__ in,
                                                    float* __restrict__ out) {
    const int gwave = (blockIdx.x * 256 + threadIdx.x) >> 6;  // global wave id = row id
    const int lane  = threadIdx.x & 63;
    if (gwave >= BB * CC * HH) return;

    const float4* rowv = reinterpret_cast<const float4*>(in + (size_t)gwave * WW);
    float4* outv       = reinterpret_cast<float4*>(out + (size_t)gwave * WW);

    float4 a = rowv[lane];
    float4 b = rowv[lane + 64];

    float m = fmaxf(fmaxf(fmaxf(a.x, a.y), fmaxf(a.z, a.w)),
                    fmaxf(fmaxf(b.x, b.y), fmaxf(b.z, b.w)));
    #pragma unroll
    for (int off = 32; off; off >>= 1) m = fmaxf(m, __shfl_xor(m, off));

    a.x = expf(a.x - m); a.y = expf(a.y - m); a.z = expf(a.z - m); a.w = expf(a.w - m);
    b.x = expf(b.x - m); b.y = expf(b.y - m); b.z = expf(b.z - m); b.w = expf(b.w - m);

    float s = (a.x + a.y + a.z + a.w) + (b.x + b.y + b.z + b.w);
    #pragma unroll
    for (int off = 32; off; off >>= 1) s += __shfl_xor(s, off);

    const float inv = 1.0f / s;
    a.x *= inv; a.y *= inv; a.z *= inv; a.w *= inv;
    b.x *= inv; b.y *= inv; b.z *= inv; b.w *= inv;
    outv[lane]      = a;
    outv[lane + 64] = b;
}

// ---------------- fused: conv + bilateral condense + compat (+ epilogue softmax) ------------
// one block per (b, h); 128 threads, each owns 4 consecutive w (float4) for all 4 classes.
__global__ __launch_bounds__(128) void crf_fused(const float* __restrict__ Uin,
                                                 const float* __restrict__ M,
                                                 const float* __restrict__ BF,
                                                 float* __restrict__ Uout,
                                                 float* __restrict__ Oout,
                                                 const int final_iter,
                                                 const float k1, const float k2,
                                                 const float k4, const float k5) {
    __shared__ float u_lds[CC][3][520];
    __shared__ float m_lds[3][520];
    __shared__ float red[2][CC];

    const int bh = blockIdx.x;
    const int b  = bh >> 6;
    const int h  = bh & 63;
    const int t  = threadIdx.x;     // 0..127
    const int w0 = t << 2;          // base w of this thread's float4

    // ---- stage 3 rows (h-1,h,h+1) of U (4 classes) and mask into LDS, zero-padded ----
    const float4 z4 = {0.f, 0.f, 0.f, 0.f};
    #pragma unroll
    for (int r = 0; r < 3; ++r) {
        const int hr = h + r - 1;
        const bool v = (unsigned)hr < (unsigned)HH;
        #pragma unroll
        for (int c = 0; c < CC; ++c) {
            float4 val = v ? *reinterpret_cast<const float4*>(
                                 &Uin[(((size_t)b * CC + c) * HH + hr) * WW + w0]) : z4;
            *reinterpret_cast<float4*>(&u_lds[c][r][4 + w0]) = val;
        }
        float4 mval = v ? *reinterpret_cast<const float4*>(
                              &M[((size_t)b * HH + hr) * WW + w0]) : z4;
        *reinterpret_cast<float4*>(&m_lds[r][4 + w0]) = mval;
    }
    if (t < 4) {
        #pragma unroll
        for (int r = 0; r < 3; ++r) {
            #pragma unroll
            for (int c = 0; c < CC; ++c) { u_lds[c][r][t] = 0.f; u_lds[c][r][516 + t] = 0.f; }
            m_lds[r][t] = 0.f; m_lds[r][516 + t] = 0.f;
        }
    }
    __syncthreads();

    // ---- preload mask windows: win[i] = m[w0 - 4 + i], i in 0..11 ----
    float mwin[3][12];
    #pragma unroll
    for (int r = 0; r < 3; ++r)
        #pragma unroll
        for (int j = 0; j < 3; ++j)
            *reinterpret_cast<float4*>(&mwin[r][4 * j]) =
                *reinterpret_cast<const float4*>(&m_lds[r][w0 + 4 * j]);

    const float kw_row[3][5] = {{k5, k2, k1, k2, k5},
                                {k4, k1, 0.f, k1, k4},
                                {k5, k2, k1, k2, k5}};

    float ang[CC][4], bi[CC][4], uc[CC][4];
    const float mc[4] = {mwin[1][4], mwin[1][5], mwin[1][6], mwin[1][7]};

    #pragma unroll
    for (int c = 0; c < CC; ++c) {
        const float* bfp = BF + (((size_t)b * CC + c) * 14) * (size_t)HW + (size_t)h * WW + w0;
        float a[4] = {0.f, 0.f, 0.f, 0.f}, d[4] = {0.f, 0.f, 0.f, 0.f};
        int n = 0;
        #pragma unroll
        for (int r = 0; r < 3; ++r) {
            float uwin[12];
            #pragma unroll
            for (int j = 0; j < 3; ++j)
                *reinterpret_cast<float4*>(&uwin[4 * j]) =
                    *reinterpret_cast<const float4*>(&u_lds[c][r][w0 + 4 * j]);
            if (r == 1) {
                uc[c][0] = uwin[4]; uc[c][1] = uwin[5];
                uc[c][2] = uwin[6]; uc[c][3] = uwin[7];
            }
            #pragma unroll
            for (int da = 0; da < 5; ++da) {
                if (r == 1 && da == 2) continue;   // center tap excluded
                const float kv = kw_row[r][da];
                const float4 bfv = *reinterpret_cast<const float4*>(&bfp[(size_t)n * HW]);
                const float bfa[4] = {bfv.x, bfv.y, bfv.z, bfv.w};
                #pragma unroll
                for (int q = 0; q < 4; ++q) {
                    const float uv = uwin[q + da + 2];
                    a[q] = fmaf(kv, uv, a[q]);
                    d[q] = fmaf(bfa[q], uv * mwin[r][q + da + 2], d[q]);
                }
                ++n;
            }
        }
        #pragma unroll
        for (int q = 0; q < 4; ++q) {
            ang[c][q] = a[q];
            bi[c][q]  = d[q] * mc[q] * a[q];   // condensed * mask * bi_ang (bi_ang == ang)
        }
    }

    // ---- compatibility transform + unary add ----
    float o[CC][4];
    #pragma unroll
    for (int q = 0; q < 4; ++q) {
        const float sa = ang[0][q] + ang[1][q] + ang[2][q] + ang[3][q];
        const float sb = bi[0][q] + bi[1][q] + bi[2][q] + bi[3][q];
        #pragma unroll
        for (int c = 0; c < CC; ++c)
            o[c][q] = uc[c][q] + 0.02f * (sa - ang[c][q]) + 0.1f * (sb - bi[c][q]);
    }

    if (final_iter) {
        #pragma unroll
        for (int c = 0; c < CC; ++c) {
            const float4 v = {o[c][0], o[c][1], o[c][2], o[c][3]};
            *reinterpret_cast<float4*>(&Oout[(((size_t)b * CC + c) * HH + h) * WW + w0]) = v;
        }
        return;
    }

    // ---- epilogue softmax over W per class -> next unary ----
    const int lane = t & 63, wv = t >> 6;

    float mx[CC];
    #pragma unroll
    for (int c = 0; c < CC; ++c) {
        float v = fmaxf(fmaxf(o[c][0], o[c][1]), fmaxf(o[c][2], o[c][3]));
        #pragma unroll
        for (int off = 32; off; off >>= 1) v = fmaxf(v, __shfl_xor(v, off));
        mx[c] = v;
    }
    if (lane == 0) {
        #pragma unroll
        for (int c = 0; c < CC; ++c) red[wv][c] = mx[c];
    }
    __syncthreads();
    float gmx[CC];
    #pragma unroll
    for (int c = 0; c < CC; ++c) gmx[c] = fmaxf(red[0][c], red[1][c]);
    __syncthreads();

    float e[CC][4], sm[CC];
    #pragma unroll
    for (int c = 0; c < CC; ++c) {
        float s = 0.f;
        #pragma unroll
        for (int q = 0; q < 4; ++q) { e[c][q] = expf(o[c][q] - gmx[c]); s += e[c][q]; }
        #pragma unroll
        for (int off = 32; off; off >>= 1) s += __shfl_xor(s, off);
        sm[c] = s;
    }
    if (lane == 0) {
        #pragma unroll
        for (int c = 0; c < CC; ++c) red[wv][c] = sm[c];
    }
    __syncthreads();
    #pragma unroll
    for (int c = 0; c < CC; ++c) {
        const float inv = 1.f / (red[0][c] + red[1][c]);
        const float4 v = {e[c][0] * inv, e[c][1] * inv, e[c][2] * inv, e[c][3] * inv};
        *reinterpret_cast<float4*>(&Uout[(((size_t)b * CC + c) * HH + h) * WW + w0]) = v;
    }
}

extern "C" void kernel_launch(void* const* d_in, const int* in_sizes, int n_in,
                              void* d_out, int out_size, void* d_ws, size_t ws_size,
                              hipStream_t stream) {
    const float* x    = (const float*)d_in[0];
    const float* mask = (const float*)d_in[1];
    const float* bf   = (const float*)d_in[2];
    float* out = (float*)d_out;
    float* U0  = (float*)d_ws;                         // 16 MB
    float* U1  = U0 + (size_t)BB * CC * HH * WW;       // 16 MB

    const double ts2 = 2.0 * 0.9 * 0.9;
    const float k1 = (float)exp(-1.0 / ts2);
    const float k2 = (float)exp(-2.0 / ts2);
    const float k4 = (float)exp(-4.0 / ts2);
    const float k5 = (float)exp(-5.0 / ts2);

    const dim3 sgrid(2048), sblk(256);     // 8192 rows / 4 per block
    const dim3 fgrid(BB * HH), fblk(128);  // 2048 blocks

    softmax_rows<<<sgrid, sblk, 0, stream>>>(x, U0);
    crf_fused<<<fgrid, fblk, 0, stream>>>(U0, mask, bf, U1, out, 0, k1, k2, k4, k5);
    crf_fused<<<fgrid, fblk, 0, stream>>>(U1, mask, bf, U0, out, 0, k1, k2, k4, k5);
    crf_fused<<<fgrid, fblk, 0, stream>>>(U0, mask, bf, U0, out, 1, k1, k2, k4, k5);
}

// Round 9
// 439.797 us; speedup vs baseline: 1.0021x; 1.0021x over previous
//
#include <hip/hip_runtime.h>
#include <math.h>

#define BB 32
#define CC 4
#define HH 64
#define WW 512
#define HW (HH * WW)

// ---------------- softmax over W (last axis), one wave (64 lanes) per row ----------------
__global__ __launch_bounds__(256) void softmax_rows(const float* __restrict__ in,
                                                    float* __restrict__ out) {
    const int gwave = (blockIdx.x * 256 + threadIdx.x) >> 6;  // global wave id = row id
    const int lane  = threadIdx.x & 63;
    if (gwave >= BB * CC * HH) return;

    const float4* rowv = reinterpret_cast<const float4*>(in + (size_t)gwave * WW);
    float4* outv       = reinterpret_cast<float4*>(out + (size_t)gwave * WW);

    float4 a = rowv[lane];
    float4 b = rowv[lane + 64];

    float m = fmaxf(fmaxf(fmaxf(a.x, a.y), fmaxf(a.z, a.w)),
                    fmaxf(fmaxf(b.x, b.y), fmaxf(b.z, b.w)));
    #pragma unroll
    for (int off = 32; off; off >>= 1) m = fmaxf(m, __shfl_xor(m, off));

    a.x = expf(a.x - m); a.y = expf(a.y - m); a.z = expf(a.z - m); a.w = expf(a.w - m);
    b.x = expf(b.x - m); b.y = expf(b.y - m); b.z = expf(b.z - m); b.w = expf(b.w - m);

    float s = (a.x + a.y + a.z + a.w) + (b.x + b.y + b.z + b.w);
    #pragma unroll
    for (int off = 32; off; off >>= 1) s += __shfl_xor(s, off);

    const float inv = 1.0f / s;
    a.x *= inv; a.y *= inv; a.z *= inv; a.w *= inv;
    b.x *= inv; b.y *= inv; b.z *= inv; b.w *= inv;
    outv[lane]      = a;
    outv[lane + 64] = b;
}

// ---------------- fused: conv + bilateral condense + compat (+ epilogue softmax) ------------
// one block per (b, h); 128 threads, each owns 4 consecutive w (float4) for all 4 classes.
// `rev` flips the blockIdx->tile mapping so consecutive dispatches traverse the 235 MB
// bilateral_filters tensor in opposite orders (L3 zigzag: start where the last pass ended).
__global__ __launch_bounds__(128) void crf_fused(const float* __restrict__ Uin,
                                                 const float* __restrict__ M,
                                                 const float* __restrict__ BF,
                                                 float* __restrict__ Uout,
                                                 float* __restrict__ Oout,
                                                 const int final_iter,
                                                 const int rev,
                                                 const float k1, const float k2,
                                                 const float k4, const float k5) {
    __shared__ float u_lds[CC][3][520];
    __shared__ float m_lds[3][520];
    __shared__ float red[2][CC];

    const int bh = rev ? ((BB * HH - 1) - blockIdx.x) : blockIdx.x;
    const int b  = bh >> 6;
    const int h  = bh & 63;
    const int t  = threadIdx.x;     // 0..127
    const int w0 = t << 2;          // base w of this thread's float4

    // ---- stage 3 rows (h-1,h,h+1) of U (4 classes) and mask into LDS, zero-padded ----
    const float4 z4 = {0.f, 0.f, 0.f, 0.f};
    #pragma unroll
    for (int r = 0; r < 3; ++r) {
        const int hr = h + r - 1;
        const bool v = (unsigned)hr < (unsigned)HH;
        #pragma unroll
        for (int c = 0; c < CC; ++c) {
            float4 val = v ? *reinterpret_cast<const float4*>(
                                 &Uin[(((size_t)b * CC + c) * HH + hr) * WW + w0]) : z4;
            *reinterpret_cast<float4*>(&u_lds[c][r][4 + w0]) = val;
        }
        float4 mval = v ? *reinterpret_cast<const float4*>(
                              &M[((size_t)b * HH + hr) * WW + w0]) : z4;
        *reinterpret_cast<float4*>(&m_lds[r][4 + w0]) = mval;
    }
    if (t < 4) {
        #pragma unroll
        for (int r = 0; r < 3; ++r) {
            #pragma unroll
            for (int c = 0; c < CC; ++c) { u_lds[c][r][t] = 0.f; u_lds[c][r][516 + t] = 0.f; }
            m_lds[r][t] = 0.f; m_lds[r][516 + t] = 0.f;
        }
    }
    __syncthreads();

    // ---- preload mask windows: win[i] = m[w0 - 4 + i], i in 0..11 ----
    float mwin[3][12];
    #pragma unroll
    for (int r = 0; r < 3; ++r)
        #pragma unroll
        for (int j = 0; j < 3; ++j)
            *reinterpret_cast<float4*>(&mwin[r][4 * j]) =
                *reinterpret_cast<const float4*>(&m_lds[r][w0 + 4 * j]);

    const float kw_row[3][5] = {{k5, k2, k1, k2, k5},
                                {k4, k1, 0.f, k1, k4},
                                {k5, k2, k1, k2, k5}};

    float ang[CC][4], bi[CC][4], uc[CC][4];
    const float mc[4] = {mwin[1][4], mwin[1][5], mwin[1][6], mwin[1][7]};

    #pragma unroll
    for (int c = 0; c < CC; ++c) {
        const float* bfp = BF + (((size_t)b * CC + c) * 14) * (size_t)HW + (size_t)h * WW + w0;
        float a[4] = {0.f, 0.f, 0.f, 0.f}, d[4] = {0.f, 0.f, 0.f, 0.f};
        int n = 0;
        #pragma unroll
        for (int r = 0; r < 3; ++r) {
            float uwin[12];
            #pragma unroll
            for (int j = 0; j < 3; ++j)
                *reinterpret_cast<float4*>(&uwin[4 * j]) =
                    *reinterpret_cast<const float4*>(&u_lds[c][r][w0 + 4 * j]);
            if (r == 1) {
                uc[c][0] = uwin[4]; uc[c][1] = uwin[5];
                uc[c][2] = uwin[6]; uc[c][3] = uwin[7];
            }
            #pragma unroll
            for (int da = 0; da < 5; ++da) {
                if (r == 1 && da == 2) continue;   // center tap excluded
                const float kv = kw_row[r][da];
                const float4 bfv = *reinterpret_cast<const float4*>(&bfp[(size_t)n * HW]);
                const float bfa[4] = {bfv.x, bfv.y, bfv.z, bfv.w};
                #pragma unroll
                for (int q = 0; q < 4; ++q) {
                    const float uv = uwin[q + da + 2];
                    a[q] = fmaf(kv, uv, a[q]);
                    d[q] = fmaf(bfa[q], uv * mwin[r][q + da + 2], d[q]);
                }
                ++n;
            }
        }
        #pragma unroll
        for (int q = 0; q < 4; ++q) {
            ang[c][q] = a[q];
            bi[c][q]  = d[q] * mc[q] * a[q];   // condensed * mask * bi_ang (bi_ang == ang)
        }
    }

    // ---- compatibility transform + unary add ----
    float o[CC][4];
    #pragma unroll
    for (int q = 0; q < 4; ++q) {
        const float sa = ang[0][q] + ang[1][q] + ang[2][q] + ang[3][q];
        const float sb = bi[0][q] + bi[1][q] + bi[2][q] + bi[3][q];
        #pragma unroll
        for (int c = 0; c < CC; ++c)
            o[c][q] = uc[c][q] + 0.02f * (sa - ang[c][q]) + 0.1f * (sb - bi[c][q]);
    }

    if (final_iter) {
        #pragma unroll
        for (int c = 0; c < CC; ++c) {
            const float4 v = {o[c][0], o[c][1], o[c][2], o[c][3]};
            *reinterpret_cast<float4*>(&Oout[(((size_t)b * CC + c) * HH + h) * WW + w0]) = v;
        }
        return;
    }

    // ---- epilogue softmax over W per class -> next unary ----
    const int lane = t & 63, wv = t >> 6;

    float mx[CC];
    #pragma unroll
    for (int c = 0; c < CC; ++c) {
        float v = fmaxf(fmaxf(o[c][0], o[c][1]), fmaxf(o[c][2], o[c][3]));
        #pragma unroll
        for (int off = 32; off; off >>= 1) v = fmaxf(v, __shfl_xor(v, off));
        mx[c] = v;
    }
    if (lane == 0) {
        #pragma unroll
        for (int c = 0; c < CC; ++c) red[wv][c] = mx[c];
    }
    __syncthreads();
    float gmx[CC];
    #pragma unroll
    for (int c = 0; c < CC; ++c) gmx[c] = fmaxf(red[0][c], red[1][c]);
    __syncthreads();

    float e[CC][4], sm[CC];
    #pragma unroll
    for (int c = 0; c < CC; ++c) {
        float s = 0.f;
        #pragma unroll
        for (int q = 0; q < 4; ++q) { e[c][q] = expf(o[c][q] - gmx[c]); s += e[c][q]; }
        #pragma unroll
        for (int off = 32; off; off >>= 1) s += __shfl_xor(s, off);
        sm[c] = s;
    }
    if (lane == 0) {
        #pragma unroll
        for (int c = 0; c < CC; ++c) red[wv][c] = sm[c];
    }
    __syncthreads();
    #pragma unroll
    for (int c = 0; c < CC; ++c) {
        const float inv = 1.f / (red[0][c] + red[1][c]);
        const float4 v = {e[c][0] * inv, e[c][1] * inv, e[c][2] * inv, e[c][3] * inv};
        *reinterpret_cast<float4*>(&Uout[(((size_t)b * CC + c) * HH + h) * WW + w0]) = v;
    }
}

extern "C" void kernel_launch(void* const* d_in, const int* in_sizes, int n_in,
                              void* d_out, int out_size, void* d_ws, size_t ws_size,
                              hipStream_t stream) {
    const float* x    = (const float*)d_in[0];
    const float* mask = (const float*)d_in[1];
    const float* bf   = (const float*)d_in[2];
    float* out = (float*)d_out;
    float* U0  = (float*)d_ws;                         // 16 MB
    float* U1  = U0 + (size_t)BB * CC * HH * WW;       // 16 MB

    const double ts2 = 2.0 * 0.9 * 0.9;
    const float k1 = (float)exp(-1.0 / ts2);
    const float k2 = (float)exp(-2.0 / ts2);
    const float k4 = (float)exp(-4.0 / ts2);
    const float k5 = (float)exp(-5.0 / ts2);

    const dim3 sgrid(2048), sblk(256);     // 8192 rows / 4 per block
    const dim3 fgrid(BB * HH), fblk(128);  // 2048 blocks

    // multi-dispatch (kernel boundaries give device-wide coherence); zigzag BF traversal
    softmax_rows<<<sgrid, sblk, 0, stream>>>(x, U0);
    crf_fused<<<fgrid, fblk, 0, stream>>>(U0, mask, bf, U1, out, 0, 0, k1, k2, k4, k5);
    crf_fused<<<fgrid, fblk, 0, stream>>>(U1, mask, bf, U0, out, 0, 1, k1, k2, k4, k5);
    crf_fused<<<fgrid, fblk, 0, stream>>>(U0, mask, bf, U0, out, 1, 0, k1, k2, k4, k5);
}